// Round 4
// baseline (444.760 us; speedup 1.0000x reference)
//
#include <hip/hip_runtime.h>

#define M_DIM 8192
#define IN_DIM 4096
#define OUT_DIM 4096

typedef int   v4i  __attribute__((ext_vector_type(4)));
typedef int   v16i __attribute__((ext_vector_type(16)));
typedef short v8s  __attribute__((ext_vector_type(8)));
typedef float v4f  __attribute__((ext_vector_type(4)));
typedef float v16f __attribute__((ext_vector_type(16)));

static __device__ __forceinline__ int pack4(int a, int b, int c, int d) {
    return (a & 255) | ((b & 255) << 8) | ((c & 255) << 16) | ((d & 255) << 24);
}

static __device__ __forceinline__ short f2bf(float f) {  // RNE
    unsigned u = __float_as_uint(f);
    u = (u + 0x7FFFu + ((u >> 16) & 1u)) >> 16;
    return (short)u;
}

static __device__ __forceinline__ short i2bf(int v) {  // exact for |v| <= 128
    float f = (float)v;
    return (short)(__float_as_uint(f) >> 16);
}

static __device__ __forceinline__ float gelu_tanh(float u) {
    float u2 = u * u;
    float p  = fmaf(u2, 0.0356774081f, 0.7978845608f);
    float v  = u * p;
    float e  = __builtin_amdgcn_exp2f(v * 2.8853900818f);
    return u - u * __builtin_amdgcn_rcpf(e + 1.0f);
}

static __device__ __forceinline__ void async_cp16(const signed char* g, signed char* l) {
    __builtin_amdgcn_global_load_lds((const __attribute__((address_space(1))) void*)g,
                                     (__attribute__((address_space(3))) void*)l, 16, 0, 0);
}

// Tiled operand layout (shared by pack kernels and GEMM staging):
//   buf[((tile*64 + kk)*16 + gp)*1024 + lane*16 + j] = src[row][k]
//   row = tile*256 + (gp>>1)*32 + (lane&31)
//   k   = kk*64 + (gp&1)*32 + (lane>>5)*16 + j ,  j in [0,16)
// GEMM staging reads are 1KB-contiguous; frag ds_read_b128 = base + lane*16 (0 conflicts).

// ---------------- lora_a fp32 -> bf16 ----------------
__global__ __launch_bounds__(256) void pack_a_kernel(const float* __restrict__ la,
                                                     short* __restrict__ a16) {
    size_t i = ((size_t)blockIdx.x * 256 + threadIdx.x) * 8;
    const float4* p = (const float4*)(la + i);
    float4 a = p[0], b = p[1];
    v8s o;
    o[0] = f2bf(a.x); o[1] = f2bf(a.y); o[2] = f2bf(a.z); o[3] = f2bf(a.w);
    o[4] = f2bf(b.x); o[5] = f2bf(b.y); o[6] = f2bf(b.z); o[7] = f2bf(b.w);
    *(v8s*)(a16 + i) = o;
}

// ---------------- weight int32 -> int8 in tiled layout (gather) ----------------
__global__ __launch_bounds__(256) void pack_w_kernel(const int* __restrict__ w,
                                                     signed char* __restrict__ w8t) {
    const int flat = blockIdx.x * 256 + threadIdx.x;  // 16B slot id
    const int l  = flat & 63;
    const int gp = (flat >> 6) & 15;
    const int kk = (flat >> 10) & 63;
    const int bn = flat >> 16;
    const int n = bn * 256 + ((gp >> 1) << 5) + (l & 31);
    const int k = kk * 64 + ((gp & 1) << 5) + ((l >> 5) << 4);
    const int4* p = (const int4*)(w + (size_t)n * IN_DIM + k);
    int4 a = p[0], b = p[1], c = p[2], d = p[3];
    int4 o;
    o.x = pack4(a.x, a.y, a.z, a.w);
    o.y = pack4(b.x, b.y, b.z, b.w);
    o.z = pack4(c.x, c.y, c.z, c.w);
    o.w = pack4(d.x, d.y, d.z, d.w);
    *(int4*)(w8t + (size_t)flat * 16) = o;
}

// ---- fused: x int32 -> int8 tiled layout  AND  T[m][r] = sum_k x[m][k]*A[r][k] ----
__global__ __launch_bounds__(256) void pack_x_lora_kernel(const int* __restrict__ x,
                                                          const short* __restrict__ a16,
                                                          signed char* __restrict__ x8t,
                                                          float* __restrict__ T) {
    __shared__ float red[4 * 256];
    const int tid = threadIdx.x;
    const int lane = tid & 63, wv = tid >> 6;
    const int fr = lane & 15, fq = lane >> 4;
    const int m0 = blockIdx.x * 16;
    const int bm = m0 >> 8;
    const int g  = (m0 >> 5) & 7;
    const int l5 = (m0 & 16) + fr;           // row & 31
    const int row = m0 + fr;

    v4f acc = {0.f, 0.f, 0.f, 0.f};
#pragma unroll 2
    for (int kt = 0; kt < 32; ++kt) {
        const int k  = wv * 1024 + kt * 32 + fq * 8;
        const int4* xp = (const int4*)(x + (size_t)row * IN_DIM + k);
        int4 a = xp[0], b = xp[1];
        const int kk = k >> 6, c = (k >> 4) & 3, j8 = (k >> 3) & 1;
        int2 pk = make_int2(pack4(a.x, a.y, a.z, a.w), pack4(b.x, b.y, b.z, b.w));
        *(int2*)(x8t + ((size_t)((bm * 64 + kk) * 16 + g * 2 + (c >> 1))) * 1024 +
                 ((c & 1) * 32 + l5) * 16 + j8 * 8) = pk;
        v8s xa;
        xa[0] = i2bf(a.x); xa[1] = i2bf(a.y); xa[2] = i2bf(a.z); xa[3] = i2bf(a.w);
        xa[4] = i2bf(b.x); xa[5] = i2bf(b.y); xa[6] = i2bf(b.z); xa[7] = i2bf(b.w);
        v8s aa = *(const v8s*)(a16 + (size_t)fr * IN_DIM + k);
        acc = __builtin_amdgcn_mfma_f32_16x16x32_bf16(xa, aa, acc, 0, 0, 0);
    }
    *(v4f*)&red[wv * 256 + lane * 4] = acc;
    __syncthreads();

    float s = red[tid] + red[256 + tid] + red[512 + tid] + red[768 + tid];
    const int sl = tid >> 2, j = tid & 3;
    const int r16 = ((sl >> 4) << 2) + j, col = sl & 15;  // C/D 16x16 layout
    T[(size_t)(m0 + r16) * 16 + col] = s;
}

// ------- i8 MFMA GEMM: 128x256 block, 64x128 wave tile (acc=128 regs -> 2 waves/SIMD) -------
__global__ __launch_bounds__(256, 2) void q8_gemm_kernel(
    const signed char* __restrict__ x8t, const signed char* __restrict__ w8t,
    const float* __restrict__ Tp, const float* __restrict__ lbm,
    const float* __restrict__ bias, const float* __restrict__ xsc,
    const float* __restrict__ wsc, const int* __restrict__ gflag,
    float* __restrict__ out) {
    __shared__ __align__(16) signed char smem[49152];  // 2 x (A 8K | B 16K)

    const int tid  = threadIdx.x;
    const int lane = tid & 63;
    const int wv   = tid >> 6;
    const int wm   = wv >> 1, wn = wv & 1;
    // XCD swizzle: each XCD owns A rows [xcd*1024, +1024) = 4MB ~= its L2
    const int b   = blockIdx.x;
    const int xcd = b & 7, idx = b >> 3;          // idx in [0,128)
    const int bm  = xcd * 8 + (idx & 7);          // [0,64)  (128-row tiles)
    const int bn  = idx >> 3;                     // [0,16)  (256-col tiles)

    const int lofs = lane * 16;
    // A: 256-row supertile st = bm>>1, half h = bm&1 -> gp = h*8 + c
    const signed char* Abase = x8t + (size_t)(bm >> 1) * (64 * 16 * 1024) + (bm & 1) * 8192;
    const signed char* Bbase = w8t + (size_t)bn * (64 * 16 * 1024);

    v16i acc[2][4];
    {
        v16i z;
#pragma unroll
        for (int i = 0; i < 16; ++i) z[i] = 0;
#pragma unroll
        for (int mt = 0; mt < 2; ++mt)
#pragma unroll
            for (int nt = 0; nt < 4; ++nt) acc[mt][nt] = z;
    }

    // staging: 24 x 1KB chunks per K-step (A:0..7, B:8..23); wave wv stages 6
    // prologue: tile 0 -> buffer 0
#pragma unroll
    for (int i = 0; i < 6; ++i) {
        const int c = wv * 6 + i;
        const signed char* src = (c < 8) ? (Abase + (size_t)c * 1024 + lofs)
                                         : (Bbase + (size_t)(c - 8) * 1024 + lofs);
        async_cp16(src, smem + c * 1024);
    }

    for (int kk = 0; kk < 64; ++kk) {
        __syncthreads();  // buffer kk&1 ready; other buffer's readers done
        if (kk + 1 < 64) {
            const int nb = (kk + 1) & 1;
            const size_t ko = (size_t)(kk + 1) * 16 * 1024;
#pragma unroll
            for (int i = 0; i < 6; ++i) {
                const int c = wv * 6 + i;
                const signed char* src = (c < 8) ? (Abase + ko + (size_t)c * 1024 + lofs)
                                                 : (Bbase + ko + (size_t)(c - 8) * 1024 + lofs);
                async_cp16(src, smem + nb * 24576 + c * 1024);
            }
        }
        const signed char* Ab = smem + (kk & 1) * 24576;
        const signed char* Bb = Ab + 8192;
#pragma unroll
        for (int s = 0; s < 2; ++s) {
            v4i av[2], bv[4];
#pragma unroll
            for (int mt = 0; mt < 2; ++mt)
                av[mt] = *(const v4i*)(Ab + ((wm * 2 + mt) * 2 + s) * 1024 + lofs);
#pragma unroll
            for (int nt = 0; nt < 4; ++nt)
                bv[nt] = *(const v4i*)(Bb + ((wn * 4 + nt) * 2 + s) * 1024 + lofs);
#pragma unroll
            for (int mt = 0; mt < 2; ++mt)
#pragma unroll
                for (int nt = 0; nt < 4; ++nt)
                    acc[mt][nt] = __builtin_amdgcn_mfma_i32_32x32x32_i8(
                        av[mt], bv[nt], acc[mt][nt], 0, 0, 0);
        }
    }

    // ---------------- epilogue: operands straight from global ----------------
    const int mbase = bm * 128 + wm * 64;
    const int nbase = bn * 256 + wn * 128;
    const int l31 = lane & 31, lh = lane >> 5;
    const bool dg = (*gflag) != 0;

    v8s tf[2], bf[4];
#pragma unroll
    for (int mt = 0; mt < 2; ++mt) {
        const float* t0 = Tp + (size_t)(mbase + mt * 32 + l31) * 16 + lh * 8;
        v8s v;
#pragma unroll
        for (int j = 0; j < 8; ++j) v[j] = f2bf(t0[j]);
        tf[mt] = v;
    }
#pragma unroll
    for (int nt = 0; nt < 4; ++nt) {
        const float* bp = lbm + (size_t)(nbase + nt * 32 + l31) * 16 + lh * 8;
        v8s v;
#pragma unroll
        for (int j = 0; j < 8; ++j) v[j] = f2bf(bp[j]);
        bf[nt] = v;
    }
    float wsa[4], bba[4];
#pragma unroll
    for (int nt = 0; nt < 4; ++nt) {
        const int col = nbase + nt * 32 + l31;
        wsa[nt] = wsc[col];
        bba[nt] = bias[col];
    }

#pragma unroll
    for (int mt = 0; mt < 2; ++mt) {
        const int rowb = mbase + mt * 32 + lh * 4;
        float4 xs0 = *(const float4*)(xsc + rowb);
        float4 xs1 = *(const float4*)(xsc + rowb + 8);
        float4 xs2 = *(const float4*)(xsc + rowb + 16);
        float4 xs3 = *(const float4*)(xsc + rowb + 24);
        float xsv[16] = {xs0.x, xs0.y, xs0.z, xs0.w, xs1.x, xs1.y, xs1.z, xs1.w,
                         xs2.x, xs2.y, xs2.z, xs2.w, xs3.x, xs3.y, xs3.z, xs3.w};
#pragma unroll
        for (int nt = 0; nt < 4; ++nt) {
            v16f fa;
#pragma unroll
            for (int i = 0; i < 16; ++i) fa[i] = (float)acc[mt][nt][i] * wsa[nt];
            // fa += T-frag * lora_b-frag (C/D layout shared with the i8 32x32 MFMA)
            fa = __builtin_amdgcn_mfma_f32_32x32x16_bf16(tf[mt], bf[nt], fa, 0, 0, 0);
            const int col = nbase + nt * 32 + l31;
#pragma unroll
            for (int r = 0; r < 16; ++r) {
                float u = fmaf(xsv[r], fa[r], bba[nt]);
                if (dg) u = gelu_tanh(u);
                out[(size_t)(rowb + (r & 3) + 8 * (r >> 2)) * OUT_DIM + col] = u;
            }
        }
    }
}

extern "C" void kernel_launch(void* const* d_in, const int* in_sizes, int n_in,
                              void* d_out, int out_size, void* d_ws, size_t ws_size,
                              hipStream_t stream) {
    const int*   x     = (const int*)d_in[0];
    const int*   wt    = (const int*)d_in[1];
    const float* bias  = (const float*)d_in[2];
    const float* xsc   = (const float*)d_in[3];
    const float* wsc   = (const float*)d_in[4];
    const float* la    = (const float*)d_in[5];
    const float* lb    = (const float*)d_in[6];
    const int*   gflag = (const int*)d_in[7];
    float* out = (float*)d_out;

    signed char* x8t = (signed char*)d_ws;
    signed char* w8t = x8t + (size_t)M_DIM * IN_DIM;
    float* T = (float*)(w8t + (size_t)OUT_DIM * IN_DIM);
    short* a16 = (short*)w8t;  // alias: consumed by pack_x_lora BEFORE pack_w writes w8t

    pack_a_kernel<<<16 * IN_DIM / (8 * 256), 256, 0, stream>>>(la, a16);
    pack_x_lora_kernel<<<M_DIM / 16, 256, 0, stream>>>(x, a16, x8t, T);
    pack_w_kernel<<<(size_t)OUT_DIM * IN_DIM / (16 * 256), 256, 0, stream>>>(wt, w8t);
    q8_gemm_kernel<<<(M_DIM / 128) * (OUT_DIM / 256), 256, 0, stream>>>(
        x8t, w8t, T, lb, bias, xsc, wsc, gflag, out);
}